// Round 2
// baseline (392.420 us; speedup 1.0000x reference)
//
#include <hip/hip_runtime.h>
#include <math.h>

#define CNUM 19
#define NB 4
#define HW 589824            // 768*768
#define NPIX 2359296         // NB*HW

// k_main: 256 threads x 4 px = 1024 px/block -> grid (576, 4) = 9216 waves
#define TPB 256
#define PXT 4
#define TILE (TPB * PXT)     // 1024; HW % TILE == 0

// k_hist: 256 threads x 8 px = 2048 px/block -> grid (288, 4) = 4608 waves
#define HPX 8
#define HTILE (256 * HPX)    // 2048

// ---------------------------------------------------------------- workspace
// Per-image accumulators padded to separate cache lines: 576 blocks/image
// each fire 5 double atomics; keep images from serializing on one line.
struct alignas(64) ImgAcc {
  double num_seg, den_seg, num_att, den_att, bce;
  double pad[3];
};

struct Ws {
  unsigned int hist_seg[NB][CNUM];
  unsigned int hist_att[NB][CNUM];
  unsigned int pos_num;
  unsigned int neg_num;
  ImgAcc acc[NB];
};

// ---------------------------------------------------------------- init
__global__ void k_init(Ws* ws) {
  unsigned int* p = (unsigned int*)ws;
  const int nw = (int)(sizeof(Ws) / 4);
  for (int i = threadIdx.x; i < nw; i += blockDim.x) p[i] = 0u;
}

// ---------------------------------------------------------------- histograms
__global__ __launch_bounds__(256, 4) void k_hist(const int* __restrict__ segmask,
                                                 const float* __restrict__ edgein,
                                                 const int* __restrict__ edgemask,
                                                 Ws* __restrict__ ws) {
  const int n   = blockIdx.y;
  const int tid = threadIdx.x;
  const int base = n * HW + blockIdx.x * HTILE + tid * 4;

  unsigned int cs[CNUM], ca[CNUM];
  #pragma unroll
  for (int c = 0; c < CNUM; ++c) { cs[c] = 0u; ca[c] = 0u; }
  unsigned int cp = 0u, cn = 0u;

  #pragma unroll 2
  for (int it = 0; it < HPX / 4; ++it) {
    const int idx = base + it * 1024;
    int4   sv = *reinterpret_cast<const int4*>(segmask + idx);
    float4 e  = *reinterpret_cast<const float4*>(edgein + idx);
    int4   mv = *reinterpret_cast<const int4*>(edgemask + idx);
    int   sa[4] = {sv.x, sv.y, sv.z, sv.w};
    float ea[4] = {e.x, e.y, e.z, e.w};
    int   ma[4] = {mv.x, mv.y, mv.z, mv.w};
    #pragma unroll
    for (int p = 0; p < 4; ++p) {
      const int s = sa[p];
      const bool inb = ((unsigned)s) < (unsigned)CNUM;
      const unsigned long long attm = __ballot(ea[p] > 0.8f);
      #pragma unroll
      for (int c = 0; c < CNUM; ++c) {
        unsigned long long bm = __ballot(inb && (s == c));
        cs[c] += (unsigned)__popcll(bm);
        ca[c] += (unsigned)__popcll(bm & attm);
      }
      cp += (unsigned)__popcll(__ballot(ma[p] == 1));
      cn += (unsigned)__popcll(__ballot(ma[p] == 0));
    }
  }

  __shared__ unsigned int red[4][2 * CNUM + 2];
  const int wave = tid >> 6;
  const int lane = tid & 63;
  if (lane == 0) {
    #pragma unroll
    for (int c = 0; c < CNUM; ++c) { red[wave][c] = cs[c]; red[wave][CNUM + c] = ca[c]; }
    red[wave][2 * CNUM] = cp;
    red[wave][2 * CNUM + 1] = cn;
  }
  __syncthreads();
  if (tid < 2 * CNUM + 2) {
    unsigned int v = red[0][tid] + red[1][tid] + red[2][tid] + red[3][tid];
    if (tid < CNUM)               atomicAdd(&ws->hist_seg[n][tid], v);
    else if (tid < 2 * CNUM)      atomicAdd(&ws->hist_att[n][tid - CNUM], v);
    else if (tid == 2 * CNUM)     atomicAdd(&ws->pos_num, v);
    else                          atomicAdd(&ws->neg_num, v);
  }
}

// ---------------------------------------------------------------- main pass
// Latency-bound fix: 9216 waves (full subscription) + <=64 VGPR (8 waves/SIMD)
// instead of 2304 waves @ 196 VGPR (2/SIMD). Per channel each thread loads one
// float4 (block reads 4KB contiguous per channel), 19 independent loads the
// compiler can pipeline deeply within the 64-reg budget.
__global__ __launch_bounds__(TPB, 8) void k_main(const float* __restrict__ segin,
                                                 const float* __restrict__ edgein,
                                                 const int* __restrict__ segmask,
                                                 const int* __restrict__ edgemask,
                                                 const Ws* __restrict__ ws,
                                                 Ws* __restrict__ wsw) {
  const int n = blockIdx.y;
  const int t = threadIdx.x;
  const int tile0 = blockIdx.x * TILE;

  __shared__ float lws[CNUM], lwa[CNUM];
  __shared__ float redlds[TPB / 64][5];

  if (t < CNUM) {
    float total = 0.f;
    #pragma unroll
    for (int i = 0; i < CNUM; ++i) total += (float)ws->hist_seg[n][i];
    float bins = (float)ws->hist_seg[n][t];
    lws[t] = (bins != 0.f ? (1.0f - bins / total) : 0.f) + 1.0f;
  } else if (t >= 64 && t < 64 + CNUM) {
    int c = t - 64;
    float total = 0.f;
    #pragma unroll
    for (int i = 0; i < CNUM; ++i) total += (float)ws->hist_att[n][i];
    float bins = (float)ws->hist_att[n][c];
    lwa[c] = (bins != 0.f ? (1.0f - bins / total) : 0.f) + 1.0f;
  }
  const unsigned int pn = ws->pos_num, nn = ws->neg_num;
  const float inv_sum = 1.0f / (float)(pn + nn);
  const float wpos = (float)nn * inv_sum;
  const float wneg = (float)pn * inv_sum;
  __syncthreads();

  // masks/edge for this thread's 4 consecutive pixels
  const int pxoff = n * HW + tile0 + t * 4;
  int4   tm = *reinterpret_cast<const int4*>(segmask + pxoff);
  float4 ev = *reinterpret_cast<const float4*>(edgein + pxoff);
  int4   em = *reinterpret_cast<const int4*>(edgemask + pxoff);

  int tcv[PXT];
  unsigned int validbits = 0u;   // bit j: segmask != 255
  unsigned int embits = 0u;      // 2 bits per j: edgemask value
  {
    int ta[4] = {tm.x, tm.y, tm.z, tm.w};
    int ea[4] = {em.x, em.y, em.z, em.w};
    #pragma unroll
    for (int j = 0; j < 4; ++j) {
      tcv[j] = min(max(ta[j], 0), CNUM - 1);
      validbits |= (ta[j] != 255) ? (1u << j) : 0u;
      embits |= ((unsigned)(ea[j] & 3)) << (2 * j);
    }
  }

  float sacc[PXT] = {0.f, 0.f, 0.f, 0.f};
  float xt[PXT]   = {0.f, 0.f, 0.f, 0.f};

  const float* cb = segin + (size_t)n * CNUM * HW + tile0 + t * 4;
  #pragma unroll
  for (int c = 0; c < CNUM; ++c) {
    float4 v = *reinterpret_cast<const float4*>(cb + (size_t)c * HW);
    float va[4] = {v.x, v.y, v.z, v.w};
    #pragma unroll
    for (int j = 0; j < 4; ++j) {
      sacc[j] += __expf(va[j]);
      xt[j] = (tcv[j] == c) ? va[j] : xt[j];
    }
  }

  float acc_num_s = 0.f, acc_den_s = 0.f, acc_num_a = 0.f, acc_den_a = 0.f, acc_bce = 0.f;
  {
    float ea[4] = {ev.x, ev.y, ev.z, ev.w};
    #pragma unroll
    for (int j = 0; j < PXT; ++j) {
      float lp = xt[j] - __logf(sacc[j]);
      bool valid = (validbits >> j) & 1u;
      float pw_s = valid ? lws[tcv[j]] : 0.f;
      acc_num_s -= pw_s * lp;
      acc_den_s += pw_s;

      float e = ea[j];
      bool valida = valid && (e > 0.8f);
      float pw_a = valida ? lwa[tcv[j]] : 0.f;
      acc_num_a -= pw_a * lp;
      acc_den_a += pw_a;

      int emv = (int)((embits >> (2 * j)) & 3u);
      float bce = fmaxf(e, 0.f) - e * (float)emv + log1pf(__expf(-fabsf(e)));
      float wb = (emv == 1) ? wpos : ((emv == 0) ? wneg : 0.f);
      acc_bce += wb * bce;
    }
  }

  #pragma unroll
  for (int off = 32; off > 0; off >>= 1) {
    acc_num_s += __shfl_down(acc_num_s, off);
    acc_den_s += __shfl_down(acc_den_s, off);
    acc_num_a += __shfl_down(acc_num_a, off);
    acc_den_a += __shfl_down(acc_den_a, off);
    acc_bce   += __shfl_down(acc_bce, off);
  }
  const int wave = t >> 6;
  const int lane = t & 63;
  if (lane == 0) {
    redlds[wave][0] = acc_num_s; redlds[wave][1] = acc_den_s;
    redlds[wave][2] = acc_num_a; redlds[wave][3] = acc_den_a;
    redlds[wave][4] = acc_bce;
  }
  __syncthreads();
  if (t == 0) {
    float r0 = redlds[0][0] + redlds[1][0] + redlds[2][0] + redlds[3][0];
    float r1 = redlds[0][1] + redlds[1][1] + redlds[2][1] + redlds[3][1];
    float r2 = redlds[0][2] + redlds[1][2] + redlds[2][2] + redlds[3][2];
    float r3 = redlds[0][3] + redlds[1][3] + redlds[2][3] + redlds[3][3];
    float r4 = redlds[0][4] + redlds[1][4] + redlds[2][4] + redlds[3][4];
    atomicAdd(&wsw->acc[n].num_seg, (double)r0);
    atomicAdd(&wsw->acc[n].den_seg, (double)r1);
    atomicAdd(&wsw->acc[n].num_att, (double)r2);
    atomicAdd(&wsw->acc[n].den_att, (double)r3);
    atomicAdd(&wsw->acc[n].bce,     (double)r4);
  }
}

// ---------------------------------------------------------------- finalize
__global__ void k_final(const Ws* __restrict__ ws, float* __restrict__ out) {
  if (threadIdx.x == 0 && blockIdx.x == 0) {
    double segl = 0.0, attl = 0.0, bces = 0.0;
    for (int i = 0; i < NB; ++i) {
      segl += ws->acc[i].num_seg / ws->acc[i].den_seg;
      attl += ws->acc[i].num_att / ws->acc[i].den_att;
      bces += ws->acc[i].bce;
    }
    double edgel = bces / (double)NPIX;
    out[0] = (float)(segl + 0.3 * edgel + 0.1 * attl);
  }
}

// ---------------------------------------------------------------- launch
extern "C" void kernel_launch(void* const* d_in, const int* in_sizes, int n_in,
                              void* d_out, int out_size, void* d_ws, size_t ws_size,
                              hipStream_t stream) {
  const float* segin   = (const float*)d_in[0];
  const float* edgein  = (const float*)d_in[1];
  const int*   segmask = (const int*)d_in[2];
  const int*   edgemask= (const int*)d_in[3];
  Ws* ws = (Ws*)d_ws;
  float* out = (float*)d_out;

  hipLaunchKernelGGL(k_init,  dim3(1),               dim3(128), 0, stream, ws);
  hipLaunchKernelGGL(k_hist,  dim3(HW / HTILE, NB),  dim3(256), 0, stream, segmask, edgein, edgemask, ws);
  hipLaunchKernelGGL(k_main,  dim3(HW / TILE, NB),   dim3(TPB), 0, stream, segin, edgein, segmask, edgemask, ws, ws);
  hipLaunchKernelGGL(k_final, dim3(1),               dim3(1),   0, stream, ws, out);
}

// Round 3
// 322.366 us; speedup vs baseline: 1.2173x; 1.2173x over previous
//
#include <hip/hip_runtime.h>
#include <math.h>

#define CNUM 19
#define NB 4
#define HW 589824            // 768*768
#define NPIX 2359296         // NB*HW

// k_main: 256 threads x 4 px = 1024 px/block -> grid (576, 4) = 9216 waves
#define TPB 256
#define PXT 4
#define TILE (TPB * PXT)     // 1024; HW % TILE == 0

// k_hist: 256 threads x 8 px = 2048 px/block -> grid (288, 4) = 4608 waves
#define HPX 8
#define HTILE (256 * HPX)    // 2048

// ---------------------------------------------------------------- workspace
struct alignas(64) ImgAcc {
  double num_seg, den_seg, num_att, den_att, bce;
  double pad[3];
};

struct Ws {
  unsigned int hist_seg[NB][CNUM];
  unsigned int hist_att[NB][CNUM];
  unsigned int pos_num;
  unsigned int neg_num;
  ImgAcc acc[NB];
};

// ---------------------------------------------------------------- init
__global__ void k_init(Ws* ws) {
  unsigned int* p = (unsigned int*)ws;
  const int nw = (int)(sizeof(Ws) / 4);
  for (int i = threadIdx.x; i < nw; i += blockDim.x) p[i] = 0u;
}

// ---------------------------------------------------------------- histograms
__global__ __launch_bounds__(256, 4) void k_hist(const int* __restrict__ segmask,
                                                 const float* __restrict__ edgein,
                                                 const int* __restrict__ edgemask,
                                                 Ws* __restrict__ ws) {
  const int n   = blockIdx.y;
  const int tid = threadIdx.x;
  const int base = n * HW + blockIdx.x * HTILE + tid * 4;

  unsigned int cs[CNUM], ca[CNUM];
  #pragma unroll
  for (int c = 0; c < CNUM; ++c) { cs[c] = 0u; ca[c] = 0u; }
  unsigned int cp = 0u, cn = 0u;

  #pragma unroll 2
  for (int it = 0; it < HPX / 4; ++it) {
    const int idx = base + it * 1024;
    int4   sv = *reinterpret_cast<const int4*>(segmask + idx);
    float4 e  = *reinterpret_cast<const float4*>(edgein + idx);
    int4   mv = *reinterpret_cast<const int4*>(edgemask + idx);
    int   sa[4] = {sv.x, sv.y, sv.z, sv.w};
    float ea[4] = {e.x, e.y, e.z, e.w};
    int   ma[4] = {mv.x, mv.y, mv.z, mv.w};
    #pragma unroll
    for (int p = 0; p < 4; ++p) {
      const int s = sa[p];
      const bool inb = ((unsigned)s) < (unsigned)CNUM;
      const unsigned long long attm = __ballot(ea[p] > 0.8f);
      #pragma unroll
      for (int c = 0; c < CNUM; ++c) {
        unsigned long long bm = __ballot(inb && (s == c));
        cs[c] += (unsigned)__popcll(bm);
        ca[c] += (unsigned)__popcll(bm & attm);
      }
      cp += (unsigned)__popcll(__ballot(ma[p] == 1));
      cn += (unsigned)__popcll(__ballot(ma[p] == 0));
    }
  }

  __shared__ unsigned int red[4][2 * CNUM + 2];
  const int wave = tid >> 6;
  const int lane = tid & 63;
  if (lane == 0) {
    #pragma unroll
    for (int c = 0; c < CNUM; ++c) { red[wave][c] = cs[c]; red[wave][CNUM + c] = ca[c]; }
    red[wave][2 * CNUM] = cp;
    red[wave][2 * CNUM + 1] = cn;
  }
  __syncthreads();
  if (tid < 2 * CNUM + 2) {
    unsigned int v = red[0][tid] + red[1][tid] + red[2][tid] + red[3][tid];
    if (tid < CNUM)               atomicAdd(&ws->hist_seg[n][tid], v);
    else if (tid < 2 * CNUM)      atomicAdd(&ws->hist_att[n][tid - CNUM], v);
    else if (tid == 2 * CNUM)     atomicAdd(&ws->pos_num, v);
    else                          atomicAdd(&ws->neg_num, v);
  }
}

// ---------------------------------------------------------------- main pass
// Round-2 post-mortem: __launch_bounds__(256,8) -> 32-VGPR cap -> 187MB of
// scratch spill writes. Fix: (256,4) -> 64-VGPR budget (still 8 waves/SIMD
// when the allocator lands <=64), and shrink the live set across the
// 19-channel loop by deferring edgein/edgemask loads to the epilogue
// (L2/L3-resident after k_hist; no extra HBM traffic).
__global__ __launch_bounds__(TPB, 4) void k_main(const float* __restrict__ segin,
                                                 const float* __restrict__ edgein,
                                                 const int* __restrict__ segmask,
                                                 const int* __restrict__ edgemask,
                                                 const Ws* __restrict__ ws,
                                                 Ws* __restrict__ wsw) {
  const int n = blockIdx.y;
  const int t = threadIdx.x;
  const int tile0 = blockIdx.x * TILE;

  __shared__ float lws[CNUM], lwa[CNUM];
  __shared__ float redlds[TPB / 64][5];

  if (t < CNUM) {
    float total = 0.f;
    #pragma unroll
    for (int i = 0; i < CNUM; ++i) total += (float)ws->hist_seg[n][i];
    float bins = (float)ws->hist_seg[n][t];
    lws[t] = (bins != 0.f ? (1.0f - bins / total) : 0.f) + 1.0f;
  } else if (t >= 64 && t < 64 + CNUM) {
    int c = t - 64;
    float total = 0.f;
    #pragma unroll
    for (int i = 0; i < CNUM; ++i) total += (float)ws->hist_att[n][i];
    float bins = (float)ws->hist_att[n][c];
    lwa[c] = (bins != 0.f ? (1.0f - bins / total) : 0.f) + 1.0f;
  }
  const unsigned int pn = ws->pos_num, nn = ws->neg_num;
  const float inv_sum = 1.0f / (float)(pn + nn);
  const float wpos = (float)nn * inv_sum;
  const float wneg = (float)pn * inv_sum;
  __syncthreads();

  const int pxoff = n * HW + tile0 + t * 4;

  // Only segmask is needed across the channel loop.
  int4 tm = *reinterpret_cast<const int4*>(segmask + pxoff);
  int tcv[PXT];
  unsigned int validbits = 0u;   // bit j: segmask != 255
  {
    int ta[4] = {tm.x, tm.y, tm.z, tm.w};
    #pragma unroll
    for (int j = 0; j < 4; ++j) {
      tcv[j] = min(max(ta[j], 0), CNUM - 1);
      validbits |= (ta[j] != 255) ? (1u << j) : 0u;
    }
  }

  float sacc[PXT] = {0.f, 0.f, 0.f, 0.f};
  float xt[PXT]   = {0.f, 0.f, 0.f, 0.f};

  const float* cb = segin + (size_t)n * CNUM * HW + tile0 + t * 4;
  #pragma unroll
  for (int c = 0; c < CNUM; ++c) {
    float4 v = *reinterpret_cast<const float4*>(cb + (size_t)c * HW);
    float va[4] = {v.x, v.y, v.z, v.w};
    #pragma unroll
    for (int j = 0; j < 4; ++j) {
      sacc[j] += __expf(va[j]);
      xt[j] = (tcv[j] == c) ? va[j] : xt[j];
    }
  }

  // Epilogue: load edge data now (L2/L3-hot), keep loop live-set small.
  float4 ev = *reinterpret_cast<const float4*>(edgein + pxoff);
  int4   em = *reinterpret_cast<const int4*>(edgemask + pxoff);

  float acc_num_s = 0.f, acc_den_s = 0.f, acc_num_a = 0.f, acc_den_a = 0.f, acc_bce = 0.f;
  {
    float ea[4] = {ev.x, ev.y, ev.z, ev.w};
    int   ma[4] = {em.x, em.y, em.z, em.w};
    #pragma unroll
    for (int j = 0; j < PXT; ++j) {
      float lp = xt[j] - __logf(sacc[j]);
      bool valid = (validbits >> j) & 1u;
      float pw_s = valid ? lws[tcv[j]] : 0.f;
      acc_num_s -= pw_s * lp;
      acc_den_s += pw_s;

      float e = ea[j];
      bool valida = valid && (e > 0.8f);
      float pw_a = valida ? lwa[tcv[j]] : 0.f;
      acc_num_a -= pw_a * lp;
      acc_den_a += pw_a;

      int emv = ma[j];
      float bce = fmaxf(e, 0.f) - e * (float)emv + log1pf(__expf(-fabsf(e)));
      float wb = (emv == 1) ? wpos : ((emv == 0) ? wneg : 0.f);
      acc_bce += wb * bce;
    }
  }

  #pragma unroll
  for (int off = 32; off > 0; off >>= 1) {
    acc_num_s += __shfl_down(acc_num_s, off);
    acc_den_s += __shfl_down(acc_den_s, off);
    acc_num_a += __shfl_down(acc_num_a, off);
    acc_den_a += __shfl_down(acc_den_a, off);
    acc_bce   += __shfl_down(acc_bce, off);
  }
  const int wave = t >> 6;
  const int lane = t & 63;
  if (lane == 0) {
    redlds[wave][0] = acc_num_s; redlds[wave][1] = acc_den_s;
    redlds[wave][2] = acc_num_a; redlds[wave][3] = acc_den_a;
    redlds[wave][4] = acc_bce;
  }
  __syncthreads();
  if (t == 0) {
    float r0 = redlds[0][0] + redlds[1][0] + redlds[2][0] + redlds[3][0];
    float r1 = redlds[0][1] + redlds[1][1] + redlds[2][1] + redlds[3][1];
    float r2 = redlds[0][2] + redlds[1][2] + redlds[2][2] + redlds[3][2];
    float r3 = redlds[0][3] + redlds[1][3] + redlds[2][3] + redlds[3][3];
    float r4 = redlds[0][4] + redlds[1][4] + redlds[2][4] + redlds[3][4];
    atomicAdd(&wsw->acc[n].num_seg, (double)r0);
    atomicAdd(&wsw->acc[n].den_seg, (double)r1);
    atomicAdd(&wsw->acc[n].num_att, (double)r2);
    atomicAdd(&wsw->acc[n].den_att, (double)r3);
    atomicAdd(&wsw->acc[n].bce,     (double)r4);
  }
}

// ---------------------------------------------------------------- finalize
__global__ void k_final(const Ws* __restrict__ ws, float* __restrict__ out) {
  if (threadIdx.x == 0 && blockIdx.x == 0) {
    double segl = 0.0, attl = 0.0, bces = 0.0;
    for (int i = 0; i < NB; ++i) {
      segl += ws->acc[i].num_seg / ws->acc[i].den_seg;
      attl += ws->acc[i].num_att / ws->acc[i].den_att;
      bces += ws->acc[i].bce;
    }
    double edgel = bces / (double)NPIX;
    out[0] = (float)(segl + 0.3 * edgel + 0.1 * attl);
  }
}

// ---------------------------------------------------------------- launch
extern "C" void kernel_launch(void* const* d_in, const int* in_sizes, int n_in,
                              void* d_out, int out_size, void* d_ws, size_t ws_size,
                              hipStream_t stream) {
  const float* segin   = (const float*)d_in[0];
  const float* edgein  = (const float*)d_in[1];
  const int*   segmask = (const int*)d_in[2];
  const int*   edgemask= (const int*)d_in[3];
  Ws* ws = (Ws*)d_ws;
  float* out = (float*)d_out;

  hipLaunchKernelGGL(k_init,  dim3(1),               dim3(128), 0, stream, ws);
  hipLaunchKernelGGL(k_hist,  dim3(HW / HTILE, NB),  dim3(256), 0, stream, segmask, edgein, edgemask, ws);
  hipLaunchKernelGGL(k_main,  dim3(HW / TILE, NB),   dim3(TPB), 0, stream, segin, edgein, segmask, edgemask, ws, ws);
  hipLaunchKernelGGL(k_final, dim3(1),               dim3(1),   0, stream, ws, out);
}